// Round 19
// baseline (122.193 us; speedup 1.0000x reference)
//
#include <hip/hip_runtime.h>
#include <hip/hip_fp16.h>
#include <cmath>

#define Tn 8192
#define Dn 512
#define Fn 2048
#define En 8

typedef _Float16 f16x8 __attribute__((ext_vector_type(8)));
typedef _Float16 f16x4 __attribute__((ext_vector_type(4)));
typedef float f32x4 __attribute__((ext_vector_type(4)));

#define MAXTILES 136    // ceil(Tn/64) + En = 8*17, divisible by 8 XCDs

__device__ __forceinline__ void gload16(const void* g, void* l) {
    __builtin_amdgcn_global_load_lds(
        (const __attribute__((address_space(1))) unsigned int*)g,
        (__attribute__((address_space(3))) unsigned int*)l, 16, 0, 0);
}

// A&S 7.1.26 rational erf, |eps| <= 1.5e-7
__device__ __forceinline__ float fast_gelu(float v) {
    float z = fabsf(v) * 0.70710678118654752f;
    float t = 1.0f / fmaf(0.3275911f, z, 1.0f);
    float p = t * fmaf(t, fmaf(t, fmaf(t, fmaf(t, 1.061405429f, -1.453152027f),
                                       1.421413741f), -0.284496736f), 0.254829592f);
    float e = __expf(-z * z);
    float erfa = fmaf(-p, e, 1.0f);                 // erf(|z|)
    float phi = 0.5f + copysignf(0.5f * erfa, v);   // 0.5*(1+erf(v/sqrt2))
    return v * phi;
}

// ---------------- fused: router (blocks 0..255) + weight transpose (blocks 256..4351) ----------------
__global__ __launch_bounds__(256) void prep_kernel(
    const float* __restrict__ x, const float* __restrict__ Ws,
    const float* __restrict__ bs, _Float16* __restrict__ x16,
    int* __restrict__ route, float* __restrict__ scale,
    int* __restrict__ poslocal, int* __restrict__ blockCounts,
    const float* __restrict__ W1, const float* __restrict__ W2,
    _Float16* __restrict__ W1T, _Float16* __restrict__ W2T)
{
    __shared__ float tilebuf[64][65];
    __shared__ int hist[8];
    const int tid = threadIdx.x;

    if (blockIdx.x < 256) {
        // ---------- router ----------
        if (tid < 8) hist[tid] = 0;
        __syncthreads();

        const int lane = tid & 63;
        const int w = tid >> 6;
        const int tokBase = blockIdx.x * 32 + w * 8;

        float wreg[8][8];
#pragma unroll
        for (int j = 0; j < 4; ++j) {
            const float4* p = reinterpret_cast<const float4*>(Ws + (4 * lane + j) * En);
            float4 a = p[0], b = p[1];
            wreg[j][0] = a.x; wreg[j][1] = a.y; wreg[j][2] = a.z; wreg[j][3] = a.w;
            wreg[j][4] = b.x; wreg[j][5] = b.y; wreg[j][6] = b.z; wreg[j][7] = b.w;
        }
#pragma unroll
        for (int j = 0; j < 4; ++j) {
            const float4* p = reinterpret_cast<const float4*>(Ws + (256 + 4 * lane + j) * En);
            float4 a = p[0], b = p[1];
            wreg[4 + j][0] = a.x; wreg[4 + j][1] = a.y; wreg[4 + j][2] = a.z; wreg[4 + j][3] = a.w;
            wreg[4 + j][4] = b.x; wreg[4 + j][5] = b.y; wreg[4 + j][6] = b.z; wreg[4 + j][7] = b.w;
        }
        float bsv[8];
#pragma unroll
        for (int e = 0; e < 8; ++e) bsv[e] = bs[e];

        for (int it = 0; it < 8; ++it) {
            int t = tokBase + it;
            const float4* xr = reinterpret_cast<const float4*>(x + (size_t)t * Dn);
            float4 v0 = xr[lane];
            float4 v1 = xr[64 + lane];
            f16x4 h0, h1;
            h0[0] = (_Float16)v0.x; h0[1] = (_Float16)v0.y; h0[2] = (_Float16)v0.z; h0[3] = (_Float16)v0.w;
            h1[0] = (_Float16)v1.x; h1[1] = (_Float16)v1.y; h1[2] = (_Float16)v1.z; h1[3] = (_Float16)v1.w;
            *reinterpret_cast<f16x4*>(x16 + (size_t)t * Dn + 4 * lane) = h0;
            *reinterpret_cast<f16x4*>(x16 + (size_t)t * Dn + 256 + 4 * lane) = h1;

            float xv[8] = {v0.x, v0.y, v0.z, v0.w, v1.x, v1.y, v1.z, v1.w};
            float part[8];
#pragma unroll
            for (int e = 0; e < 8; ++e) part[e] = 0.f;
#pragma unroll
            for (int j = 0; j < 8; ++j)
#pragma unroll
                for (int e = 0; e < 8; ++e) part[e] = fmaf(xv[j], wreg[j][e], part[e]);
#pragma unroll
            for (int s = 32; s > 0; s >>= 1) {
#pragma unroll
                for (int e = 0; e < 8; ++e) part[e] += __shfl_xor(part[e], s);
            }
            if (lane == 0) {
                float lg[8];
                lg[0] = part[0] + bsv[0];
                float m = lg[0]; int am = 0;
#pragma unroll
                for (int e = 1; e < 8; ++e) {
                    lg[e] = part[e] + bsv[e];
                    if (lg[e] > m) { m = lg[e]; am = e; }   // first-max tie rule
                }
                float sum = 0.f;
#pragma unroll
                for (int e = 0; e < 8; ++e) sum += expf(lg[e] - m);
                route[t] = am;
                scale[t] = 1.0f / sum;                 // top-1 softmax prob
                poslocal[t] = atomicAdd(&hist[am], 1); // LDS atomic: local rank
            }
        }
        __syncthreads();
        if (tid < 8) blockCounts[blockIdx.x * 8 + tid] = hist[tid];
        return;
    }

    // ---------- weight transpose + fp32->fp16 ----------
    int bx = blockIdx.x - 256;
    const float* in; _Float16* outp; int R, C, tR, tC;
    if (bx < 2048) {            // W1[e]: [D][F] -> W1T[e]: [F][D]
        int e = bx >> 8, t = bx & 255;
        R = Dn; C = Fn; tR = t >> 5; tC = t & 31;
        in = W1 + (size_t)e * Dn * Fn;
        outp = W1T + (size_t)e * Dn * Fn;
    } else {                    // W2[e]: [F][D] -> W2T[e]: [D][F]
        int b2 = bx - 2048;
        int e = b2 >> 8, t = b2 & 255;
        R = Fn; C = Dn; tR = t >> 3; tC = t & 7;
        in = W2 + (size_t)e * Fn * Dn;
        outp = W2T + (size_t)e * Fn * Dn;
    }
    int r0 = tR * 64, c0 = tC * 64;
    int row = tid >> 2, cq = tid & 3;
#pragma unroll
    for (int i = 0; i < 4; ++i) {
        float4 v = *reinterpret_cast<const float4*>(in + (size_t)(r0 + row) * C + c0 + cq * 16 + i * 4);
        tilebuf[row][cq * 16 + i * 4 + 0] = v.x;
        tilebuf[row][cq * 16 + i * 4 + 1] = v.y;
        tilebuf[row][cq * 16 + i * 4 + 2] = v.z;
        tilebuf[row][cq * 16 + i * 4 + 3] = v.w;
    }
    __syncthreads();
    int col = tid >> 2, rq = tid & 3;
    f16x8 o0, o1;
#pragma unroll
    for (int i = 0; i < 8; ++i) o0[i] = (_Float16)tilebuf[rq * 16 + i][col];
#pragma unroll
    for (int i = 0; i < 8; ++i) o1[i] = (_Float16)tilebuf[rq * 16 + 8 + i][col];
    size_t base = (size_t)(c0 + col) * R + r0 + rq * 16;
    *reinterpret_cast<f16x8*>(outp + base) = o0;
    *reinterpret_cast<f16x8*>(outp + base + 8) = o1;
}

// ---------------- plan: prefix sums (no atomics) + tile table ----------------
__global__ __launch_bounds__(256) void plan_kernel(
    const int* __restrict__ blockCounts,   // [256][8]
    int* __restrict__ base,                // [256][8] out
    int* __restrict__ nTiles, int* __restrict__ tileExpert,
    int* __restrict__ tileBase, int* __restrict__ tileEnd)
{
    __shared__ int cnt[256 * 8];
    __shared__ int groupSum[32 * 8];
    __shared__ int groupBase[32 * 8];
    __shared__ int totals[8];
    __shared__ int offsets_s[8];
    const int tid = threadIdx.x;
    for (int i = tid; i < 2048; i += 256) cnt[i] = blockCounts[i];
    __syncthreads();
    const int e = tid & 7, g = tid >> 3;
    {
        int s = 0;
#pragma unroll
        for (int b = g * 8; b < g * 8 + 8; ++b) s += cnt[b * 8 + e];
        groupSum[g * 8 + e] = s;
    }
    __syncthreads();
    if (tid < 8) {
        int run = 0;
        for (int gg = 0; gg < 32; ++gg) {
            groupBase[gg * 8 + tid] = run;
            run += groupSum[gg * 8 + tid];
        }
        totals[tid] = run;
    }
    __syncthreads();
    if (tid == 0) {
        int off = 0, nt = 0;
        for (int ee = 0; ee < En; ++ee) {
            offsets_s[ee] = off;
            int c = totals[ee];
            int tiles = (c + 63) / 64;
            for (int r = 0; r < tiles; ++r) {
                tileExpert[nt] = ee;
                tileBase[nt] = off + r * 64;
                tileEnd[nt] = off + c;
                ++nt;
            }
            off += c;
        }
        *nTiles = nt;
    }
    __syncthreads();
    {
        int run = offsets_s[e] + groupBase[g * 8 + e];
#pragma unroll
        for (int b = g * 8; b < g * 8 + 8; ++b) {
            base[b * 8 + e] = run;
            run += cnt[b * 8 + e];
        }
    }
}

// ---------------- scatter: pure writes, no atomics ----------------
__global__ __launch_bounds__(256) void scatter_kernel(
    const int* __restrict__ route, const int* __restrict__ poslocal,
    const int* __restrict__ base, int* __restrict__ order)
{
    int t = blockIdx.x * 256 + threadIdx.x;
    if (t >= Tn) return;
    int e = route[t];
    int rb = t >> 5;
    order[base[rb * 8 + e] + poslocal[t]] = t;
}

// ---------------- GEMM1: h = gelu(Xg @ W1 + b1) ----------------
// EXPERIMENT: BK=32, single 8 KB LDS pair, 8 gload16 in flight (half of BK=64).
// Tests the per-CU outstanding-load / LDS concurrency cap hypothesis.
// Swizzle family from R14 (verified 0 conflicts): stage chunk (lane&3)^((row>>1)&3),
// read chunk kg^((fr>>1)&3). R18 transposed epilogue kept.
__global__ __launch_bounds__(64) void gemm1_kernel(
    const _Float16* __restrict__ x16, const _Float16* __restrict__ W1T,
    const float* __restrict__ b1, const int* __restrict__ order,
    const int* __restrict__ nTiles, const int* __restrict__ tileExpert,
    const int* __restrict__ tileBase, const int* __restrict__ tileEnd,
    _Float16* __restrict__ hbuf)
{
    __shared__ _Float16 As[64 * 32];   // 4 KB
    __shared__ _Float16 Bs[64 * 32];   // 4 KB
    const int bx = blockIdx.x;
    const int bt = (bx & 7) * 17 + (bx >> 3);   // XCD-aware: 136 = 8*17
    if (bt >= *nTiles) return;
    const int e = tileExpert[bt], rowBase = tileBase[bt], rowEnd = tileEnd[bt];
    const int nBase = blockIdx.y * 64;
    const int lane = threadIdx.x;

    // staging: pass p covers row p*16+(lane>>2), dest chunk lane&3 (linear lane*16B);
    // source logical chunk = (lane&3) ^ ((row>>1)&3) = (lane&3) ^ ((lane>>3)&3)
    const int swc = ((lane & 3) ^ ((lane >> 3) & 3)) * 8;
    const _Float16* Asrc[4];
    const _Float16* Bsrc[4];
#pragma unroll
    for (int p = 0; p < 4; ++p) {
        int r = p * 16 + (lane >> 2);
        int tok = order[min(rowBase + r, Tn - 1)];
        Asrc[p] = x16 + (size_t)tok * Dn + swc;
        Bsrc[p] = W1T + (size_t)e * Dn * Fn + (size_t)(nBase + r) * Dn + swc;
    }

#define STAGE1(kt) do {                                                  \
        _Pragma("unroll")                                                \
        for (int p = 0; p < 4; ++p) {                                    \
            gload16(Asrc[p] + (kt) * 32, As + p * 512 + lane * 8);       \
            gload16(Bsrc[p] + (kt) * 32, Bs + p * 512 + lane * 8);       \
        }                                                                \
    } while (0)

    const int fr = lane & 15;
    // read: logical chunk kg = lane>>4, phys = kg ^ ((fr>>1)&3)
    const int co = (((lane >> 4)) ^ ((fr >> 1) & 3)) * 8;

    f32x4 acc[4][4];
#pragma unroll
    for (int m = 0; m < 4; ++m)
#pragma unroll
        for (int n = 0; n < 4; ++n) acc[m][n] = {0.f, 0.f, 0.f, 0.f};

    STAGE1(0);
    const int NKT = Dn / 32;  // 16
    for (int kt = 0; kt < NKT; ++kt) {
        asm volatile("s_waitcnt vmcnt(0)" ::: "memory");
        f16x8 af[4], bf[4];
#pragma unroll
        for (int m = 0; m < 4; ++m)
            af[m] = *reinterpret_cast<const f16x8*>(As + (m * 16 + fr) * 32 + co);
#pragma unroll
        for (int n = 0; n < 4; ++n)
            bf[n] = *reinterpret_cast<const f16x8*>(Bs + (n * 16 + fr) * 32 + co);
        asm volatile("s_waitcnt lgkmcnt(0)" ::: "memory");
        if (kt + 1 < NKT) STAGE1(kt + 1);
        __builtin_amdgcn_s_setprio(1);
#pragma unroll
        for (int m = 0; m < 4; ++m)
#pragma unroll
            for (int n = 0; n < 4; ++n)
                acc[m][n] = __builtin_amdgcn_mfma_f32_16x16x32_f16(bf[n], af[m], acc[m][n], 0, 0, 0);
        __builtin_amdgcn_s_setprio(0);
    }
#undef STAGE1

    // transposed epilogue: row = m*16+fr, cols = nBase + n*16 + q*4 + (0..3)
    const int q = lane >> 4;
#pragma unroll
    for (int m = 0; m < 4; ++m) {
        int i = rowBase + m * 16 + fr;
        if (i < rowEnd) {
#pragma unroll
            for (int n = 0; n < 4; ++n) {
                float4 bb = *reinterpret_cast<const float4*>(b1 + (size_t)e * Fn + nBase + n * 16 + q * 4);
                f16x4 hv;
                hv[0] = (_Float16)fast_gelu(acc[m][n][0] + bb.x);
                hv[1] = (_Float16)fast_gelu(acc[m][n][1] + bb.y);
                hv[2] = (_Float16)fast_gelu(acc[m][n][2] + bb.z);
                hv[3] = (_Float16)fast_gelu(acc[m][n][3] + bb.w);
                *reinterpret_cast<f16x4*>(hbuf + (size_t)i * Fn + nBase + n * 16 + q * 4) = hv;
            }
        }
    }
}

// ---------------- GEMM2: out = (h @ W2 + b2) * prob ----------------
// CONTROL: unchanged R18 config (BK=64, 16 KB LDS, swapped MFMA, float4 stores).
__global__ __launch_bounds__(64) void gemm2_kernel(
    const _Float16* __restrict__ hbuf, const _Float16* __restrict__ W2T,
    const float* __restrict__ b2, const int* __restrict__ order,
    const float* __restrict__ scale,
    const int* __restrict__ nTiles, const int* __restrict__ tileExpert,
    const int* __restrict__ tileBase, const int* __restrict__ tileEnd,
    float* __restrict__ out)
{
    __shared__ _Float16 As[64 * 64];   // 8 KB
    __shared__ _Float16 Bs[64 * 64];   // 8 KB
    const int bx = blockIdx.x;
    const int bt = (bx & 7) * 17 + (bx >> 3);
    if (bt >= *nTiles) return;
    const int e = tileExpert[bt], rowBase = tileBase[bt], rowEnd = tileEnd[bt];
    const int nBase = blockIdx.y * 64;
    const int lane = threadIdx.x;

    const int swc = ((lane & 7) ^ (lane >> 3)) * 8;
    const _Float16* Asrc[8];
    const _Float16* Bsrc[8];
#pragma unroll
    for (int p = 0; p < 8; ++p) {
        int r = p * 8 + (lane >> 3);
        Asrc[p] = hbuf + (size_t)min(rowBase + r, Tn - 1) * Fn + swc;
        Bsrc[p] = W2T + (size_t)e * Fn * Dn + (size_t)(nBase + r) * Fn + swc;
    }

#define STAGE2(kt) do {                                                  \
        _Pragma("unroll")                                                \
        for (int p = 0; p < 8; ++p) {                                    \
            gload16(Asrc[p] + (kt) * 64, As + (p * 64 + lane) * 8);      \
            gload16(Bsrc[p] + (kt) * 64, Bs + (p * 64 + lane) * 8);      \
        }                                                                \
    } while (0)

    const int fr = lane & 15;
    const int off0 = (((lane >> 4))     ^ (lane & 7)) * 8;
    const int off1 = ((4 + (lane >> 4)) ^ (lane & 7)) * 8;

    f32x4 acc[4][4];
#pragma unroll
    for (int m = 0; m < 4; ++m)
#pragma unroll
        for (int n = 0; n < 4; ++n) acc[m][n] = {0.f, 0.f, 0.f, 0.f};

    STAGE2(0);
    const int NKT = Fn / 64;  // 32
    for (int kt = 0; kt < NKT; ++kt) {
        asm volatile("s_waitcnt vmcnt(0)" ::: "memory");
        f16x8 af[4][2], bf[4][2];
#pragma unroll
        for (int m = 0; m < 4; ++m) {
            af[m][0] = *reinterpret_cast<const f16x8*>(As + (m * 16 + fr) * 64 + off0);
            af[m][1] = *reinterpret_cast<const f16x8*>(As + (m * 16 + fr) * 64 + off1);
        }
#pragma unroll
        for (int n = 0; n < 4; ++n) {
            bf[n][0] = *reinterpret_cast<const f16x8*>(Bs + (n * 16 + fr) * 64 + off0);
            bf[n][1] = *reinterpret_cast<const f16x8*>(Bs + (n * 16 + fr) * 64 + off1);
        }
        asm volatile("s_waitcnt lgkmcnt(0)" ::: "memory");
        if (kt + 1 < NKT) STAGE2(kt + 1);
        __builtin_amdgcn_s_setprio(1);
#pragma unroll
        for (int ks = 0; ks < 2; ++ks)
#pragma unroll
            for (int m = 0; m < 4; ++m)
#pragma unroll
                for (int n = 0; n < 4; ++n)
                    acc[m][n] = __builtin_amdgcn_mfma_f32_16x16x32_f16(bf[n][ks], af[m][ks], acc[m][n], 0, 0, 0);
        __builtin_amdgcn_s_setprio(0);
    }
#undef STAGE2

    // transposed epilogue: row = m*16+fr, cols = nBase + n*16 + q*4 + (0..3)
    const int q = lane >> 4;
#pragma unroll
    for (int m = 0; m < 4; ++m) {
        int i = rowBase + m * 16 + fr;
        if (i < rowEnd) {
            int tok = order[i];
            float s = scale[tok];
#pragma unroll
            for (int n = 0; n < 4; ++n) {
                float4 bb = *reinterpret_cast<const float4*>(b2 + (size_t)e * Dn + nBase + n * 16 + q * 4);
                float4 ov;
                ov.x = (acc[m][n][0] + bb.x) * s;
                ov.y = (acc[m][n][1] + bb.y) * s;
                ov.z = (acc[m][n][2] + bb.z) * s;
                ov.w = (acc[m][n][3] + bb.w) * s;
                *reinterpret_cast<float4*>(out + (size_t)tok * Dn + nBase + n * 16 + q * 4) = ov;
            }
        }
    }
}

extern "C" void kernel_launch(void* const* d_in, const int* in_sizes, int n_in,
                              void* d_out, int out_size, void* d_ws, size_t ws_size,
                              hipStream_t stream) {
    const float* x  = (const float*)d_in[0];
    const float* Ws = (const float*)d_in[1];
    const float* bs = (const float*)d_in[2];
    const float* W1 = (const float*)d_in[3];
    const float* b1 = (const float*)d_in[4];
    const float* W2 = (const float*)d_in[5];
    const float* b2 = (const float*)d_in[6];
    float* out = (float*)d_out;

    char* ws = (char*)d_ws;
    int* nTiles      = (int*)(ws + 0);
    int* tileExpert  = (int*)(ws + 256);
    int* tileBase    = (int*)(ws + 1024);
    int* tileEnd     = (int*)(ws + 2048);
    int* route       = (int*)(ws + 4096);
    float* scale     = (float*)(ws + 4096 + 4 * Tn);
    int* poslocal    = (int*)(ws + 4096 + 8 * Tn);
    int* order       = (int*)(ws + 4096 + 12 * Tn);
    int* blockCounts = (int*)(ws + 4096 + 16 * Tn);
    int* base        = (int*)(ws + 4096 + 16 * Tn + 8192);
    _Float16* x16    = (_Float16*)(ws + (1 << 20));
    _Float16* W1T    = x16 + (size_t)Tn * Dn;
    _Float16* W2T    = W1T + (size_t)En * Dn * Fn;
    _Float16* hbuf   = W2T + (size_t)En * Fn * Dn;

    prep_kernel<<<256 + 4096, 256, 0, stream>>>(x, Ws, bs, x16, route, scale, poslocal,
                                                blockCounts, W1, W2, W1T, W2T);
    plan_kernel<<<1, 256, 0, stream>>>(blockCounts, base, nTiles, tileExpert, tileBase, tileEnd);
    scatter_kernel<<<Tn / 256, 256, 0, stream>>>(route, poslocal, base, order);
    gemm1_kernel<<<dim3(MAXTILES, Fn / 64), 64, 0, stream>>>(
        x16, W1T, b1, order, nTiles, tileExpert, tileBase, tileEnd, hbuf);
    gemm2_kernel<<<dim3(MAXTILES, Dn / 64), 64, 0, stream>>>(
        hbuf, W2T, b2, order, scale, nTiles, tileExpert, tileBase, tileEnd, out);
}

// Round 20
// 108.393 us; speedup vs baseline: 1.1273x; 1.1273x over previous
//
#include <hip/hip_runtime.h>
#include <hip/hip_fp16.h>
#include <cmath>

#define Tn 8192
#define Dn 512
#define Fn 2048
#define En 8

typedef _Float16 f16x8 __attribute__((ext_vector_type(8)));
typedef _Float16 f16x4 __attribute__((ext_vector_type(4)));
typedef float f32x4 __attribute__((ext_vector_type(4)));

#define MAXTILES 136    // ceil(Tn/64) + En = 8*17, divisible by 8 XCDs

__device__ __forceinline__ void gload16(const void* g, void* l) {
    __builtin_amdgcn_global_load_lds(
        (const __attribute__((address_space(1))) unsigned int*)g,
        (__attribute__((address_space(3))) unsigned int*)l, 16, 0, 0);
}

// A&S 7.1.26 rational erf, |eps| <= 1.5e-7
__device__ __forceinline__ float fast_gelu(float v) {
    float z = fabsf(v) * 0.70710678118654752f;
    float t = 1.0f / fmaf(0.3275911f, z, 1.0f);
    float p = t * fmaf(t, fmaf(t, fmaf(t, fmaf(t, 1.061405429f, -1.453152027f),
                                       1.421413741f), -0.284496736f), 0.254829592f);
    float e = __expf(-z * z);
    float erfa = fmaf(-p, e, 1.0f);                 // erf(|z|)
    float phi = 0.5f + copysignf(0.5f * erfa, v);   // 0.5*(1+erf(v/sqrt2))
    return v * phi;
}

// ---------------- fused: router (blocks 0..255) + weight transpose (blocks 256..4351) ----------------
__global__ __launch_bounds__(256) void prep_kernel(
    const float* __restrict__ x, const float* __restrict__ Ws,
    const float* __restrict__ bs, _Float16* __restrict__ x16,
    int* __restrict__ route, float* __restrict__ scale,
    int* __restrict__ poslocal, int* __restrict__ blockCounts,
    const float* __restrict__ W1, const float* __restrict__ W2,
    _Float16* __restrict__ W1T, _Float16* __restrict__ W2T)
{
    __shared__ float tilebuf[64][65];
    __shared__ int hist[8];
    const int tid = threadIdx.x;

    if (blockIdx.x < 256) {
        // ---------- router ----------
        if (tid < 8) hist[tid] = 0;
        __syncthreads();

        const int lane = tid & 63;
        const int w = tid >> 6;
        const int tokBase = blockIdx.x * 32 + w * 8;

        float wreg[8][8];
#pragma unroll
        for (int j = 0; j < 4; ++j) {
            const float4* p = reinterpret_cast<const float4*>(Ws + (4 * lane + j) * En);
            float4 a = p[0], b = p[1];
            wreg[j][0] = a.x; wreg[j][1] = a.y; wreg[j][2] = a.z; wreg[j][3] = a.w;
            wreg[j][4] = b.x; wreg[j][5] = b.y; wreg[j][6] = b.z; wreg[j][7] = b.w;
        }
#pragma unroll
        for (int j = 0; j < 4; ++j) {
            const float4* p = reinterpret_cast<const float4*>(Ws + (256 + 4 * lane + j) * En);
            float4 a = p[0], b = p[1];
            wreg[4 + j][0] = a.x; wreg[4 + j][1] = a.y; wreg[4 + j][2] = a.z; wreg[4 + j][3] = a.w;
            wreg[4 + j][4] = b.x; wreg[4 + j][5] = b.y; wreg[4 + j][6] = b.z; wreg[4 + j][7] = b.w;
        }
        float bsv[8];
#pragma unroll
        for (int e = 0; e < 8; ++e) bsv[e] = bs[e];

        for (int it = 0; it < 8; ++it) {
            int t = tokBase + it;
            const float4* xr = reinterpret_cast<const float4*>(x + (size_t)t * Dn);
            float4 v0 = xr[lane];
            float4 v1 = xr[64 + lane];
            f16x4 h0, h1;
            h0[0] = (_Float16)v0.x; h0[1] = (_Float16)v0.y; h0[2] = (_Float16)v0.z; h0[3] = (_Float16)v0.w;
            h1[0] = (_Float16)v1.x; h1[1] = (_Float16)v1.y; h1[2] = (_Float16)v1.z; h1[3] = (_Float16)v1.w;
            *reinterpret_cast<f16x4*>(x16 + (size_t)t * Dn + 4 * lane) = h0;
            *reinterpret_cast<f16x4*>(x16 + (size_t)t * Dn + 256 + 4 * lane) = h1;

            float xv[8] = {v0.x, v0.y, v0.z, v0.w, v1.x, v1.y, v1.z, v1.w};
            float part[8];
#pragma unroll
            for (int e = 0; e < 8; ++e) part[e] = 0.f;
#pragma unroll
            for (int j = 0; j < 8; ++j)
#pragma unroll
                for (int e = 0; e < 8; ++e) part[e] = fmaf(xv[j], wreg[j][e], part[e]);
#pragma unroll
            for (int s = 32; s > 0; s >>= 1) {
#pragma unroll
                for (int e = 0; e < 8; ++e) part[e] += __shfl_xor(part[e], s);
            }
            if (lane == 0) {
                float lg[8];
                lg[0] = part[0] + bsv[0];
                float m = lg[0]; int am = 0;
#pragma unroll
                for (int e = 1; e < 8; ++e) {
                    lg[e] = part[e] + bsv[e];
                    if (lg[e] > m) { m = lg[e]; am = e; }   // first-max tie rule
                }
                float sum = 0.f;
#pragma unroll
                for (int e = 0; e < 8; ++e) sum += expf(lg[e] - m);
                route[t] = am;
                scale[t] = 1.0f / sum;                 // top-1 softmax prob
                poslocal[t] = atomicAdd(&hist[am], 1); // LDS atomic: local rank
            }
        }
        __syncthreads();
        if (tid < 8) blockCounts[blockIdx.x * 8 + tid] = hist[tid];
        return;
    }

    // ---------- weight transpose + fp32->fp16 ----------
    int bx = blockIdx.x - 256;
    const float* in; _Float16* outp; int R, C, tR, tC;
    if (bx < 2048) {            // W1[e]: [D][F] -> W1T[e]: [F][D]
        int e = bx >> 8, t = bx & 255;
        R = Dn; C = Fn; tR = t >> 5; tC = t & 31;
        in = W1 + (size_t)e * Dn * Fn;
        outp = W1T + (size_t)e * Dn * Fn;
    } else {                    // W2[e]: [F][D] -> W2T[e]: [D][F]
        int b2 = bx - 2048;
        int e = b2 >> 8, t = b2 & 255;
        R = Fn; C = Dn; tR = t >> 3; tC = t & 7;
        in = W2 + (size_t)e * Fn * Dn;
        outp = W2T + (size_t)e * Fn * Dn;
    }
    int r0 = tR * 64, c0 = tC * 64;
    int row = tid >> 2, cq = tid & 3;
#pragma unroll
    for (int i = 0; i < 4; ++i) {
        float4 v = *reinterpret_cast<const float4*>(in + (size_t)(r0 + row) * C + c0 + cq * 16 + i * 4);
        tilebuf[row][cq * 16 + i * 4 + 0] = v.x;
        tilebuf[row][cq * 16 + i * 4 + 1] = v.y;
        tilebuf[row][cq * 16 + i * 4 + 2] = v.z;
        tilebuf[row][cq * 16 + i * 4 + 3] = v.w;
    }
    __syncthreads();
    int col = tid >> 2, rq = tid & 3;
    f16x8 o0, o1;
#pragma unroll
    for (int i = 0; i < 8; ++i) o0[i] = (_Float16)tilebuf[rq * 16 + i][col];
#pragma unroll
    for (int i = 0; i < 8; ++i) o1[i] = (_Float16)tilebuf[rq * 16 + 8 + i][col];
    size_t base = (size_t)(c0 + col) * R + r0 + rq * 16;
    *reinterpret_cast<f16x8*>(outp + base) = o0;
    *reinterpret_cast<f16x8*>(outp + base + 8) = o1;
}

// ---------------- plan: prefix sums (no atomics) + tile table ----------------
__global__ __launch_bounds__(256) void plan_kernel(
    const int* __restrict__ blockCounts,   // [256][8]
    int* __restrict__ base,                // [256][8] out
    int* __restrict__ nTiles, int* __restrict__ tileExpert,
    int* __restrict__ tileBase, int* __restrict__ tileEnd)
{
    __shared__ int cnt[256 * 8];
    __shared__ int groupSum[32 * 8];
    __shared__ int groupBase[32 * 8];
    __shared__ int totals[8];
    __shared__ int offsets_s[8];
    const int tid = threadIdx.x;
    for (int i = tid; i < 2048; i += 256) cnt[i] = blockCounts[i];
    __syncthreads();
    const int e = tid & 7, g = tid >> 3;
    {
        int s = 0;
#pragma unroll
        for (int b = g * 8; b < g * 8 + 8; ++b) s += cnt[b * 8 + e];
        groupSum[g * 8 + e] = s;
    }
    __syncthreads();
    if (tid < 8) {
        int run = 0;
        for (int gg = 0; gg < 32; ++gg) {
            groupBase[gg * 8 + tid] = run;
            run += groupSum[gg * 8 + tid];
        }
        totals[tid] = run;
    }
    __syncthreads();
    if (tid == 0) {
        int off = 0, nt = 0;
        for (int ee = 0; ee < En; ++ee) {
            offsets_s[ee] = off;
            int c = totals[ee];
            int tiles = (c + 63) / 64;
            for (int r = 0; r < tiles; ++r) {
                tileExpert[nt] = ee;
                tileBase[nt] = off + r * 64;
                tileEnd[nt] = off + c;
                ++nt;
            }
            off += c;
        }
        *nTiles = nt;
    }
    __syncthreads();
    {
        int run = offsets_s[e] + groupBase[g * 8 + e];
#pragma unroll
        for (int b = g * 8; b < g * 8 + 8; ++b) {
            base[b * 8 + e] = run;
            run += cnt[b * 8 + e];
        }
    }
}

// ---------------- scatter: pure writes, no atomics ----------------
__global__ __launch_bounds__(256) void scatter_kernel(
    const int* __restrict__ route, const int* __restrict__ poslocal,
    const int* __restrict__ base, int* __restrict__ order)
{
    int t = blockIdx.x * 256 + threadIdx.x;
    if (t >= Tn) return;
    int e = route[t];
    int rb = t >> 5;
    order[base[rb * 8 + e] + poslocal[t]] = t;
}

// ---------------- GEMM1: h = gelu(Xg @ W1 + b1) ----------------
// Best measured config (R13/R18): ONE WAVE per block, 64x64 tile, BK=64,
// single 16 KB LDS, gload_lds + XOR-8 swizzle (0 conflicts), vmcnt(0) loop,
// XCD swizzle, swapped-MFMA transposed fragment -> f16x4 vector stores.
__global__ __launch_bounds__(64) void gemm1_kernel(
    const _Float16* __restrict__ x16, const _Float16* __restrict__ W1T,
    const float* __restrict__ b1, const int* __restrict__ order,
    const int* __restrict__ nTiles, const int* __restrict__ tileExpert,
    const int* __restrict__ tileBase, const int* __restrict__ tileEnd,
    _Float16* __restrict__ hbuf)
{
    __shared__ _Float16 As[64 * 64];   // 8 KB
    __shared__ _Float16 Bs[64 * 64];   // 8 KB
    const int bx = blockIdx.x;
    const int bt = (bx & 7) * 17 + (bx >> 3);   // XCD-aware: 136 = 8*17
    if (bt >= *nTiles) return;
    const int e = tileExpert[bt], rowBase = tileBase[bt], rowEnd = tileEnd[bt];
    const int nBase = blockIdx.y * 64;
    const int lane = threadIdx.x;

    const int swc = ((lane & 7) ^ (lane >> 3)) * 8;
    const _Float16* Asrc[8];
    const _Float16* Bsrc[8];
#pragma unroll
    for (int p = 0; p < 8; ++p) {
        int r = p * 8 + (lane >> 3);
        int tok = order[min(rowBase + r, Tn - 1)];
        Asrc[p] = x16 + (size_t)tok * Dn + swc;
        Bsrc[p] = W1T + (size_t)e * Dn * Fn + (size_t)(nBase + r) * Dn + swc;
    }

#define STAGE1(kt) do {                                                  \
        _Pragma("unroll")                                                \
        for (int p = 0; p < 8; ++p) {                                    \
            gload16(Asrc[p] + (kt) * 64, As + (p * 64 + lane) * 8);      \
            gload16(Bsrc[p] + (kt) * 64, Bs + (p * 64 + lane) * 8);      \
        }                                                                \
    } while (0)

    const int fr = lane & 15;
    const int off0 = (((lane >> 4))     ^ (lane & 7)) * 8;
    const int off1 = ((4 + (lane >> 4)) ^ (lane & 7)) * 8;

    f32x4 acc[4][4];
#pragma unroll
    for (int m = 0; m < 4; ++m)
#pragma unroll
        for (int n = 0; n < 4; ++n) acc[m][n] = {0.f, 0.f, 0.f, 0.f};

    STAGE1(0);
    const int NKT = Dn / 64;  // 8
    for (int kt = 0; kt < NKT; ++kt) {
        asm volatile("s_waitcnt vmcnt(0)" ::: "memory");
        f16x8 af[4][2], bf[4][2];
#pragma unroll
        for (int m = 0; m < 4; ++m) {
            af[m][0] = *reinterpret_cast<const f16x8*>(As + (m * 16 + fr) * 64 + off0);
            af[m][1] = *reinterpret_cast<const f16x8*>(As + (m * 16 + fr) * 64 + off1);
        }
#pragma unroll
        for (int n = 0; n < 4; ++n) {
            bf[n][0] = *reinterpret_cast<const f16x8*>(Bs + (n * 16 + fr) * 64 + off0);
            bf[n][1] = *reinterpret_cast<const f16x8*>(Bs + (n * 16 + fr) * 64 + off1);
        }
        asm volatile("s_waitcnt lgkmcnt(0)" ::: "memory");
        if (kt + 1 < NKT) STAGE1(kt + 1);
        __builtin_amdgcn_s_setprio(1);
#pragma unroll
        for (int ks = 0; ks < 2; ++ks)
#pragma unroll
            for (int m = 0; m < 4; ++m)
#pragma unroll
                for (int n = 0; n < 4; ++n)
                    acc[m][n] = __builtin_amdgcn_mfma_f32_16x16x32_f16(bf[n][ks], af[m][ks], acc[m][n], 0, 0, 0);
        __builtin_amdgcn_s_setprio(0);
    }
#undef STAGE1

    // transposed epilogue: row = m*16+fr, cols = nBase + n*16 + q*4 + (0..3)
    const int q = lane >> 4;
    float4 bb[4];
#pragma unroll
    for (int n = 0; n < 4; ++n)
        bb[n] = *reinterpret_cast<const float4*>(b1 + (size_t)e * Fn + nBase + n * 16 + q * 4);
#pragma unroll
    for (int m = 0; m < 4; ++m) {
        int i = rowBase + m * 16 + fr;
        if (i < rowEnd) {
#pragma unroll
            for (int n = 0; n < 4; ++n) {
                f16x4 hv;
                hv[0] = (_Float16)fast_gelu(acc[m][n][0] + bb[n].x);
                hv[1] = (_Float16)fast_gelu(acc[m][n][1] + bb[n].y);
                hv[2] = (_Float16)fast_gelu(acc[m][n][2] + bb[n].z);
                hv[3] = (_Float16)fast_gelu(acc[m][n][3] + bb[n].w);
                *reinterpret_cast<f16x4*>(hbuf + (size_t)i * Fn + nBase + n * 16 + q * 4) = hv;
            }
        }
    }
}

// ---------------- GEMM2: out = (h @ W2 + b2) * prob ----------------
// Best measured config: BK=64, 16 KB LDS, swapped MFMA, float4 vector stores.
__global__ __launch_bounds__(64) void gemm2_kernel(
    const _Float16* __restrict__ hbuf, const _Float16* __restrict__ W2T,
    const float* __restrict__ b2, const int* __restrict__ order,
    const float* __restrict__ scale,
    const int* __restrict__ nTiles, const int* __restrict__ tileExpert,
    const int* __restrict__ tileBase, const int* __restrict__ tileEnd,
    float* __restrict__ out)
{
    __shared__ _Float16 As[64 * 64];   // 8 KB
    __shared__ _Float16 Bs[64 * 64];   // 8 KB
    const int bx = blockIdx.x;
    const int bt = (bx & 7) * 17 + (bx >> 3);
    if (bt >= *nTiles) return;
    const int e = tileExpert[bt], rowBase = tileBase[bt], rowEnd = tileEnd[bt];
    const int nBase = blockIdx.y * 64;
    const int lane = threadIdx.x;

    const int swc = ((lane & 7) ^ (lane >> 3)) * 8;
    const _Float16* Asrc[8];
    const _Float16* Bsrc[8];
#pragma unroll
    for (int p = 0; p < 8; ++p) {
        int r = p * 8 + (lane >> 3);
        Asrc[p] = hbuf + (size_t)min(rowBase + r, Tn - 1) * Fn + swc;
        Bsrc[p] = W2T + (size_t)e * Fn * Dn + (size_t)(nBase + r) * Fn + swc;
    }

#define STAGE2(kt) do {                                                  \
        _Pragma("unroll")                                                \
        for (int p = 0; p < 8; ++p) {                                    \
            gload16(Asrc[p] + (kt) * 64, As + (p * 64 + lane) * 8);      \
            gload16(Bsrc[p] + (kt) * 64, Bs + (p * 64 + lane) * 8);      \
        }                                                                \
    } while (0)

    const int fr = lane & 15;
    const int off0 = (((lane >> 4))     ^ (lane & 7)) * 8;
    const int off1 = ((4 + (lane >> 4)) ^ (lane & 7)) * 8;

    f32x4 acc[4][4];
#pragma unroll
    for (int m = 0; m < 4; ++m)
#pragma unroll
        for (int n = 0; n < 4; ++n) acc[m][n] = {0.f, 0.f, 0.f, 0.f};

    STAGE2(0);
    const int NKT = Fn / 64;  // 32
    for (int kt = 0; kt < NKT; ++kt) {
        asm volatile("s_waitcnt vmcnt(0)" ::: "memory");
        f16x8 af[4][2], bf[4][2];
#pragma unroll
        for (int m = 0; m < 4; ++m) {
            af[m][0] = *reinterpret_cast<const f16x8*>(As + (m * 16 + fr) * 64 + off0);
            af[m][1] = *reinterpret_cast<const f16x8*>(As + (m * 16 + fr) * 64 + off1);
        }
#pragma unroll
        for (int n = 0; n < 4; ++n) {
            bf[n][0] = *reinterpret_cast<const f16x8*>(Bs + (n * 16 + fr) * 64 + off0);
            bf[n][1] = *reinterpret_cast<const f16x8*>(Bs + (n * 16 + fr) * 64 + off1);
        }
        asm volatile("s_waitcnt lgkmcnt(0)" ::: "memory");
        if (kt + 1 < NKT) STAGE2(kt + 1);
        __builtin_amdgcn_s_setprio(1);
#pragma unroll
        for (int ks = 0; ks < 2; ++ks)
#pragma unroll
            for (int m = 0; m < 4; ++m)
#pragma unroll
                for (int n = 0; n < 4; ++n)
                    acc[m][n] = __builtin_amdgcn_mfma_f32_16x16x32_f16(bf[n][ks], af[m][ks], acc[m][n], 0, 0, 0);
        __builtin_amdgcn_s_setprio(0);
    }
#undef STAGE2

    // transposed epilogue: row = m*16+fr, cols = nBase + n*16 + q*4 + (0..3)
    const int q = lane >> 4;
    float4 bb[4];
#pragma unroll
    for (int n = 0; n < 4; ++n)
        bb[n] = *reinterpret_cast<const float4*>(b2 + (size_t)e * Dn + nBase + n * 16 + q * 4);
#pragma unroll
    for (int m = 0; m < 4; ++m) {
        int i = rowBase + m * 16 + fr;
        if (i < rowEnd) {
            int tok = order[i];
            float s = scale[tok];
#pragma unroll
            for (int n = 0; n < 4; ++n) {
                float4 ov;
                ov.x = (acc[m][n][0] + bb[n].x) * s;
                ov.y = (acc[m][n][1] + bb[n].y) * s;
                ov.z = (acc[m][n][2] + bb[n].z) * s;
                ov.w = (acc[m][n][3] + bb[n].w) * s;
                *reinterpret_cast<float4*>(out + (size_t)tok * Dn + nBase + n * 16 + q * 4) = ov;
            }
        }
    }
}

extern "C" void kernel_launch(void* const* d_in, const int* in_sizes, int n_in,
                              void* d_out, int out_size, void* d_ws, size_t ws_size,
                              hipStream_t stream) {
    const float* x  = (const float*)d_in[0];
    const float* Ws = (const float*)d_in[1];
    const float* bs = (const float*)d_in[2];
    const float* W1 = (const float*)d_in[3];
    const float* b1 = (const float*)d_in[4];
    const float* W2 = (const float*)d_in[5];
    const float* b2 = (const float*)d_in[6];
    float* out = (float*)d_out;

    char* ws = (char*)d_ws;
    int* nTiles      = (int*)(ws + 0);
    int* tileExpert  = (int*)(ws + 256);
    int* tileBase    = (int*)(ws + 1024);
    int* tileEnd     = (int*)(ws + 2048);
    int* route       = (int*)(ws + 4096);
    float* scale     = (float*)(ws + 4096 + 4 * Tn);
    int* poslocal    = (int*)(ws + 4096 + 8 * Tn);
    int* order       = (int*)(ws + 4096 + 12 * Tn);
    int* blockCounts = (int*)(ws + 4096 + 16 * Tn);
    int* base        = (int*)(ws + 4096 + 16 * Tn + 8192);
    _Float16* x16    = (_Float16*)(ws + (1 << 20));
    _Float16* W1T    = x16 + (size_t)Tn * Dn;
    _Float16* W2T    = W1T + (size_t)En * Dn * Fn;
    _Float16* hbuf   = W2T + (size_t)En * Fn * Dn;

    prep_kernel<<<256 + 4096, 256, 0, stream>>>(x, Ws, bs, x16, route, scale, poslocal,
                                                blockCounts, W1, W2, W1T, W2T);
    plan_kernel<<<1, 256, 0, stream>>>(blockCounts, base, nTiles, tileExpert, tileBase, tileEnd);
    scatter_kernel<<<Tn / 256, 256, 0, stream>>>(route, poslocal, base, order);
    gemm1_kernel<<<dim3(MAXTILES, Fn / 64), 64, 0, stream>>>(
        x16, W1T, b1, order, nTiles, tileExpert, tileBase, tileEnd, hbuf);
    gemm2_kernel<<<dim3(MAXTILES, Dn / 64), 64, 0, stream>>>(
        hbuf, W2T, b2, order, scale, nTiles, tileExpert, tileBase, tileEnd, out);
}